// Round 6
// baseline (596.415 us; speedup 1.0000x reference)
//
#include <hip/hip_runtime.h>
#include <hip/hip_bf16.h>
#include <cstddef>
#include <cstdint>

#define BB 4
#define NN 16
#define GG 64          // BB*NN
#define LL 2048
#define EE 32768
#define EF (EE + LL)   // edges + self loops
#define C0 64
#define CC 256
#define EPS 1e-5f

typedef __bf16 bf16x8 __attribute__((ext_vector_type(8)));
typedef __bf16 bf16x4 __attribute__((ext_vector_type(4)));
typedef float f32x4 __attribute__((ext_vector_type(4)));

struct __align__(8) Edge { int col; float val; };

// ---------------- init: flag detect + deg/cnt init + gstats zero ----------------
// grid 8, block 256. Block 0 wave 0 also detects int64 vs int32 edge data.

__global__ void detect_init_kernel(const int* __restrict__ ei, int* __restrict__ flag,
                                   float* __restrict__ deg, int* __restrict__ cnt,
                                   float* __restrict__ gstats) {
    int i = blockIdx.x * 256 + threadIdx.x;   // 0..2047
    if (i < LL) { deg[i] = 2.0f; cnt[i] = 1; }   // self-loop weight 2, one slot
    gstats[i * 2] = 0.0f;                         // 8 slots x 512
    gstats[i * 2 + 1] = 0.0f;
    if (blockIdx.x == 0 && threadIdx.x < 64) {
        int t = threadIdx.x;
        int bad = 0;
        for (int k = t; k < 256; k += 64) bad |= (ei[2 * k + 1] != 0) ? 1 : 0;
        int any = __any(bad);
        if (t == 0) *flag = any ? 0 : 1;  // 1 => data is int64
    }
}

// convert edges to int32 AND accumulate degree (dst known in-register)
__global__ void conv_deg_kernel(const void* __restrict__ ei, const int* __restrict__ flag,
                                int* __restrict__ e32, float* __restrict__ deg,
                                int* __restrict__ cnt) {
    int e = blockIdx.x * 256 + threadIdx.x;
    if (e >= EE) return;
    int s, d;
    if (*flag) {
        s = (int)((const long long*)ei)[e];
        d = (int)((const long long*)ei)[EE + e];
    } else {
        s = ((const int*)ei)[e];
        d = ((const int*)ei)[EE + e];
    }
    e32[e] = s;
    e32[EE + e] = d;
    atomicAdd(&deg[d], 1.0f);
    atomicAdd(&cnt[d], 1);
}

// prefix-scan of cnt -> rowptr/cursor, plus dinv = rsqrt(deg)
__global__ void scan_dinv_kernel(const int* __restrict__ cnt, const float* __restrict__ deg,
                                 int* __restrict__ rowptr, int* __restrict__ cursor,
                                 float* __restrict__ dinv) {
    __shared__ int part[256];
    int t = threadIdx.x;
    int base = t * 8;
    int loc[8];
    int s = 0;
#pragma unroll
    for (int j = 0; j < 8; ++j) {
        loc[j] = s; s += cnt[base + j];
        dinv[base + j] = rsqrtf(deg[base + j]);
    }
    part[t] = s;
    __syncthreads();
    if (t == 0) {
        int run = 0;
        for (int i = 0; i < 256; ++i) { int v = part[i]; part[i] = run; run += v; }
    }
    __syncthreads();
    int off = part[t];
#pragma unroll
    for (int j = 0; j < 8; ++j) {
        int rp = off + loc[j];
        rowptr[base + j] = rp;
        cursor[base + j] = rp;
    }
    if (t == 255) rowptr[LL] = off + s;
}

__global__ void fill_kernel(const int* __restrict__ e32, const float* __restrict__ dinv,
                            int* __restrict__ cursor, Edge* __restrict__ edges) {
    int idx = blockIdx.x * 256 + threadIdx.x;
    if (idx >= EF) return;
    int s, d; float w;
    if (idx < EE) {
        s = e32[idx]; d = e32[EE + idx];
        w = dinv[s] * dinv[d];
    } else {
        int i = idx - EE;
        s = i; d = i;
        w = 2.0f * dinv[i] * dinv[i];
    }
    int pos = atomicAdd(&cursor[d], 1);
    edges[pos].col = s;
    edges[pos].val = w;
}

// ---------------- W pre-pack: all 3 weights in one launch ----------------

__global__ void prep_w_all(const float* __restrict__ W0, const float* __restrict__ W1,
                           const float* __restrict__ W2, __bf16* __restrict__ Wf0,
                           __bf16* __restrict__ Wf1, __bf16* __restrict__ Wf2) {
    int t = blockIdx.x * 256 + threadIdx.x;
    const float* W; __bf16* Wf;
    if (t < 1024)      { W = W0; Wf = Wf0; }
    else if (t < 5120) { W = W1; Wf = Wf1; t -= 1024; }
    else if (t < 9216) { W = W2; Wf = Wf2; t -= 5120; }
    else return;
    int lane = t & 63;
    int rest = t >> 6;
    int n16 = rest & 7;
    int ks = rest >> 3;
    int col = n16 * 16 + (lane & 15);
    int k0 = ks * 32 + (lane >> 4) * 8;
    bf16x8 v;
#pragma unroll
    for (int j = 0; j < 8; ++j) v[j] = (__bf16)W[(size_t)(k0 + j) * 128 + col];
    *(bf16x8*)(Wf + (size_t)t * 8) = v;
}

// ---------------- x transpose: [g][c=64][l] -> [g][l][64] f32 ----------------

__global__ void transpose_x(const float* __restrict__ x, float* __restrict__ h) {
    __shared__ float t[32][33];
    int g = blockIdx.z, c0 = blockIdx.y * 32, l0 = blockIdx.x * 32;
    int tx = threadIdx.x, ty = threadIdx.y;  // 32 x 8
    const float* xp = x + ((size_t)g * C0 + c0) * LL + l0;
#pragma unroll
    for (int i = ty; i < 32; i += 8) t[i][tx] = xp[(size_t)i * LL + tx];  // t[c][l]
    __syncthreads();
    float* hp = h + ((size_t)g * LL + l0) * C0 + c0;
#pragma unroll
    for (int i = ty; i < 32; i += 8) hp[(size_t)i * C0 + tx] = t[tx][i];
}

// ---------------- MFMA GEMM: hw[b][l][half][n8][128] = act(A)[g][l][0:K] @ W ----------------
// BN=true: A = relu(bn(concat(a, amax_broadcast))) applied on the fly at staging.
// grid (LL/64, GG), 256 threads (4 waves). Epilogue: LDS transpose -> coalesced bf16x8 stores.

template <int K, bool BN>
__global__ __launch_bounds__(256) void gemm_mfma(const float* __restrict__ A0,
                                                 const float* __restrict__ amax,
                                                 const float* __restrict__ scb,
                                                 const __bf16* __restrict__ Wf,
                                                 __bf16* __restrict__ hw) {
    const int g = blockIdx.y;
    const int l0 = blockIdx.x * 64;
    const int tid = threadIdx.x;
    const int wid = tid >> 6;
    const int lane = tid & 63;
    __shared__ __align__(16) float smem[64 * 132];   // 33.8KB; front 8KB doubles as As
    __bf16* As = (__bf16*)smem;

    f32x4 acc[8];
#pragma unroll
    for (int nf = 0; nf < 8; ++nf) acc[nf] = (f32x4){0.f, 0.f, 0.f, 0.f};

    for (int kt = 0; kt < K / 64; ++kt) {
        // ---- stage A tile [64 rows][64 k] -> bf16 LDS, XOR-swizzled ----
#pragma unroll
        for (int it = 0; it < 4; ++it) {
            int f4 = tid + it * 256;     // 0..1023
            int row = f4 >> 4;           // 0..63
            int kq = (f4 & 15) * 4;      // 0..60
            int gk = kt * 64 + kq;
            float4 v;
            if constexpr (BN) {
                if (gk < 128)
                    v = *(const float4*)(A0 + ((size_t)g * LL + l0 + row) * 128 + gk);
                else
                    v = *(const float4*)(amax + ((size_t)(g >> 4) * LL + l0 + row) * 128 + (gk - 128));
                float4 s = *(const float4*)(scb + gk);
                float4 b = *(const float4*)(scb + 256 + gk);
                v.x = fmaxf(fmaf(v.x, s.x, b.x), 0.f);
                v.y = fmaxf(fmaf(v.y, s.y, b.y), 0.f);
                v.z = fmaxf(fmaf(v.z, s.z, b.z), 0.f);
                v.w = fmaxf(fmaf(v.w, s.w, b.w), 0.f);
            } else {
                v = *(const float4*)(A0 + ((size_t)g * LL + l0 + row) * 64 + gk);
            }
            int sidx = row * 64 + (kq ^ ((row & 7) << 3));
            bf16x4 pv = {(__bf16)v.x, (__bf16)v.y, (__bf16)v.z, (__bf16)v.w};
            *(bf16x4*)(&As[sidx]) = pv;
        }
        __syncthreads();
        // ---- MFMA over the 2 k-steps of this tile ----
#pragma unroll
        for (int ks2 = 0; ks2 < 2; ++ks2) {
            const int row = wid * 16 + (lane & 15);
            const int kk = ks2 * 32 + (lane >> 4) * 8;
            bf16x8 af = *(const bf16x8*)(&As[row * 64 + (kk ^ ((row & 7) << 3))]);
            const int ksg = kt * 2 + ks2;
            const __bf16* wp = Wf + (size_t)ksg * 8 * 512 + lane * 8;
#pragma unroll
            for (int nf = 0; nf < 8; ++nf) {
                bf16x8 bfr = *(const bf16x8*)(wp + nf * 512);
                acc[nf] = __builtin_amdgcn_mfma_f32_16x16x32_bf16(af, bfr, acc[nf], 0, 0, 0);
            }
        }
        __syncthreads();
    }
    // ---- epilogue: acc -> LDS (f32, padded) -> coalesced bf16x8 stores ----
#pragma unroll
    for (int nf = 0; nf < 8; ++nf) {
        int col = nf * 16 + (lane & 15);
#pragma unroll
        for (int j = 0; j < 4; ++j) {
            int row = wid * 16 + (lane >> 4) * 4 + j;
            smem[row * 132 + col] = acc[nf][j];
        }
    }
    __syncthreads();
    const int b_ = g >> 4, n_ = g & 15;
    const int half_ = n_ >> 3, n8_ = n_ & 7;
    const int row = tid >> 2, seg = tid & 3;
    __bf16* dst = hw + ((size_t)((b_ * LL + l0 + row) * 2 + half_) * 8 + n8_) * 128 + seg * 32;
    const float* src = smem + row * 132 + seg * 32;
#pragma unroll
    for (int q = 0; q < 4; ++q) {
        bf16x8 o;
#pragma unroll
        for (int i = 0; i < 8; ++i) o[i] = (__bf16)src[q * 8 + i];
        *(bf16x8*)(dst + q * 8) = o;
    }
}

// ---------------- fused aggregation + max-over-n + BN stats (per n-half) ----------------
// hw layout [b][l][half][n8][128] bf16: one edge => 2KB contiguous (8 graphs x 128 ch).
// One wave per (b, l, half): lane n8=lane>>3 owns graph b*16+half*8+n8, chs=lane&7 owns
// 16 channels. Edge list loaded once per wave, 2-edge unroll => 4 x 1KB gathers in flight.
// Butterfly over n8 => half-max + sum/sumsq stats. XCD-pinned: xcd = (b, half) so the 4MB
// hw half-slice exactly fits one XCD's L2. grid 4096 (8 xcd x 512 lgrp), block 256.

__global__ __launch_bounds__(256) void agg_half(const __bf16* __restrict__ hw,
                                                const float* __restrict__ bias,
                                                const int* __restrict__ rowptr,
                                                const Edge* __restrict__ edges,
                                                float* __restrict__ a,
                                                float* __restrict__ halfmax,
                                                float* __restrict__ gstats) {
    __shared__ float bl_sum[128], bl_ssq[128];
    const int tid = threadIdx.x;
    if (tid < 128) { bl_sum[tid] = 0.f; bl_ssq[tid] = 0.f; }
    __syncthreads();

    const int bid = blockIdx.x;
    const int xcd = bid & 7;
    const int b = xcd >> 1, half = xcd & 1;
    const int lgrp = bid >> 3;                 // 0..511
    const int l = lgrp * 4 + (tid >> 6);
    const int lane = tid & 63;
    const int n8 = lane >> 3;                  // 0..7
    const int chs = lane & 7;                  // ch base = chs*16

    // hw offset(b,c,half,n8,ch) = b*LL*2048 + c*2048 + (half*8+n8)*128 + ch
    const __bf16* __restrict__ base =
        hw + (size_t)b * LL * 2048 + (size_t)(half * 8 + n8) * 128 + chs * 16;
    const int j0 = rowptr[l];
    const int deg = rowptr[l + 1] - j0;

    float acc[16];
#pragma unroll
    for (int i = 0; i < 16; ++i) acc[i] = 0.0f;

    for (int d0 = 0; d0 < deg; d0 += 64) {
        const int cntE = min(64, deg - d0);
        Edge e;
        e.col = 0; e.val = 0.0f;
        if (lane < cntE) e = edges[j0 + d0 + lane];
        int d = 0;
        for (; d + 2 <= cntE; d += 2) {
            int c1 = __shfl(e.col, d);     float w1 = __shfl(e.val, d);
            int c2 = __shfl(e.col, d + 1); float w2 = __shfl(e.val, d + 1);
            const __bf16* p1 = base + (size_t)c1 * 2048;
            const __bf16* p2 = base + (size_t)c2 * 2048;
            bf16x8 va = *(const bf16x8*)p1;
            bf16x8 vb = *(const bf16x8*)(p1 + 8);
            bf16x8 vc = *(const bf16x8*)p2;
            bf16x8 vd = *(const bf16x8*)(p2 + 8);
#pragma unroll
            for (int i = 0; i < 8; ++i) {
                acc[i]     = fmaf(w1, (float)va[i], acc[i]);
                acc[8 + i] = fmaf(w1, (float)vb[i], acc[8 + i]);
            }
#pragma unroll
            for (int i = 0; i < 8; ++i) {
                acc[i]     = fmaf(w2, (float)vc[i], acc[i]);
                acc[8 + i] = fmaf(w2, (float)vd[i], acc[8 + i]);
            }
        }
        if (d < cntE) {
            int c1 = __shfl(e.col, d); float w1 = __shfl(e.val, d);
            const __bf16* p1 = base + (size_t)c1 * 2048;
            bf16x8 va = *(const bf16x8*)p1;
            bf16x8 vb = *(const bf16x8*)(p1 + 8);
#pragma unroll
            for (int i = 0; i < 8; ++i) {
                acc[i]     = fmaf(w1, (float)va[i], acc[i]);
                acc[8 + i] = fmaf(w1, (float)vb[i], acc[8 + i]);
            }
        }
    }

    // add bias (a includes bias; same for all n so max/stats consistent)
#pragma unroll
    for (int q = 0; q < 4; ++q) {
        float4 bv = *(const float4*)(bias + chs * 16 + q * 4);
        acc[q * 4 + 0] += bv.x; acc[q * 4 + 1] += bv.y;
        acc[q * 4 + 2] += bv.z; acc[q * 4 + 3] += bv.w;
    }

    // write a[g][l][128], g = b*16 + half*8 + n8
    {
        float* ap = a + ((size_t)(b * 16 + half * 8 + n8) * LL + l) * 128 + chs * 16;
#pragma unroll
        for (int q = 0; q < 4; ++q)
            *(float4*)(ap + q * 4) = make_float4(acc[q * 4], acc[q * 4 + 1],
                                                 acc[q * 4 + 2], acc[q * 4 + 3]);
    }

    // butterflies over n8 (lane bits 3,4,5): max, sum, sumsq
    float mx[16], sm[16], sq[16];
#pragma unroll
    for (int i = 0; i < 16; ++i) { mx[i] = acc[i]; sm[i] = acc[i]; sq[i] = acc[i] * acc[i]; }
#pragma unroll
    for (int st = 8; st <= 32; st <<= 1) {
#pragma unroll
        for (int i = 0; i < 16; ++i) {
            mx[i] = fmaxf(mx[i], __shfl_xor(mx[i], st));
            sm[i] += __shfl_xor(sm[i], st);
            sq[i] += __shfl_xor(sq[i], st);
        }
    }

    if (n8 == 0) {
        float* hp = halfmax + ((size_t)(b * 2 + half) * LL + l) * 128 + chs * 16;
#pragma unroll
        for (int q = 0; q < 4; ++q)
            *(float4*)(hp + q * 4) = make_float4(mx[q * 4], mx[q * 4 + 1],
                                                 mx[q * 4 + 2], mx[q * 4 + 3]);
#pragma unroll
        for (int i = 0; i < 16; ++i) {
            atomicAdd(&bl_sum[chs * 16 + i], sm[i]);
            atomicAdd(&bl_ssq[chs * 16 + i], sq[i]);
        }
    }
    __syncthreads();
    const int slot = lgrp & 7;
    if (tid < 128)
        atomicAdd(&gstats[slot * 512 + tid], bl_sum[tid]);
    else if (tid < 256)
        atomicAdd(&gstats[slot * 512 + 256 + (tid - 128)], bl_ssq[tid - 128]);
}

// ---------------- combine halves: amax = max(half0, half1) + amax BN stats ----------------
// grid 1024, block 256; thread handles one (b, lgrp-of-4, ch).

__global__ void combine_kernel(const float* __restrict__ halfmax, float* __restrict__ amax,
                               float* __restrict__ gstats) {
    __shared__ float ls[256], lq[256];
    const int tid = threadIdx.x;
    const int idx = blockIdx.x * 256 + tid;
    const int ch = idx & 127;
    const int rest = idx >> 7;            // 0..2047 = b*512 + lgrp
    const int b = rest >> 9, lgrp = rest & 511;
    float s = 0.f, q = 0.f;
#pragma unroll
    for (int i = 0; i < 4; ++i) {
        int l = lgrp * 4 + i;
        float m0 = halfmax[((size_t)(b * 2 + 0) * LL + l) * 128 + ch];
        float m1 = halfmax[((size_t)(b * 2 + 1) * LL + l) * 128 + ch];
        float m = fmaxf(m0, m1);
        amax[((size_t)b * LL + l) * 128 + ch] = m;
        s += m;
        q = fmaf(m, m, q);
    }
    ls[tid] = s; lq[tid] = q;
    __syncthreads();
    if (tid < 128) {
        s = ls[tid] + ls[tid + 128];
        q = lq[tid] + lq[tid + 128];
        int slot = blockIdx.x & 7;
        atomicAdd(&gstats[slot * 512 + 128 + tid], s);
        atomicAdd(&gstats[slot * 512 + 256 + 128 + tid], q);
    }
}

// ---------------- BN finalize: gstats -> scale/bias, self-clear ----------------

__global__ void bnfinal_kernel(float* __restrict__ gstats,
                               const float* __restrict__ gamma, const float* __restrict__ beta,
                               float* __restrict__ scb) {
    int f = threadIdx.x;  // 256
    float sm = 0.f, sq = 0.f;
#pragma unroll
    for (int s = 0; s < 8; ++s) {
        sm += gstats[s * 512 + f];
        sq += gstats[s * 512 + 256 + f];
        gstats[s * 512 + f] = 0.f;
        gstats[s * 512 + 256 + f] = 0.f;
    }
    float cntv = (f < 128) ? (float)(BB * NN * LL) : (float)(BB * LL);
    float mean = sm / cntv;
    float var = sq / cntv - mean * mean;
    float s = gamma[f] * rsqrtf(var + EPS);
    scb[f] = s;
    scb[256 + f] = beta[f] - mean * s;
}

// ---------------- final: out[g][f][l] = relu(bn(concat(a, amax))) transposed ----------------

__global__ void transpose_norm_out(const float* __restrict__ a, const float* __restrict__ amax,
                                   const float* __restrict__ scb, float* __restrict__ out) {
    __shared__ float t[64][65];
    int g = blockIdx.z, f0 = blockIdx.y * 64, l0 = blockIdx.x * 64;
    int tx = threadIdx.x, ty = threadIdx.y;  // 64 x 8
    int f = f0 + tx;
    float s = scb[f], b = scb[256 + f];
#pragma unroll
    for (int i = ty; i < 64; i += 8) {
        int l = l0 + i;
        float v;
        if (f0 < 128)
            v = a[((size_t)g * LL + l) * 128 + f];
        else
            v = amax[((size_t)(g >> 4) * LL + l) * 128 + (f - 128)];
        t[i][tx] = fmaxf(fmaf(v, s, b), 0.f);
    }
    __syncthreads();
    float* op = out + ((size_t)g * CC + f0) * LL + l0;
#pragma unroll
    for (int i = ty; i < 64; i += 8) op[(size_t)i * LL + tx] = t[tx][i];
}

// ---------------- launch ----------------

extern "C" void kernel_launch(void* const* d_in, const int* in_sizes, int n_in,
                              void* d_out, int out_size, void* d_ws, size_t ws_size,
                              hipStream_t stream) {
    const float* x = (const float*)d_in[0];
    const void* ei = d_in[1];
    const float* W[3] = {(const float*)d_in[2], (const float*)d_in[4], (const float*)d_in[6]};
    const float* bia[3] = {(const float*)d_in[3], (const float*)d_in[5], (const float*)d_in[7]};
    const float* gam[3] = {(const float*)d_in[8], (const float*)d_in[10], (const float*)d_in[12]};
    const float* bet[3] = {(const float*)d_in[9], (const float*)d_in[11], (const float*)d_in[13]};
    float* out = (float*)d_out;

    char* w = (char*)d_ws;
    float* h0     = (float*)w;  w += (size_t)GG * LL * C0 * 4;    // 33.5MB
    float* a      = (float*)w;  w += (size_t)GG * LL * 128 * 4;   // 67MB
    __bf16* hw    = (__bf16*)w; w += (size_t)GG * LL * 128 * 2;   // 33.5MB [b][l][half][n8][128]
    float* amax   = (float*)w;  w += (size_t)BB * LL * 128 * 4;   // 4MB
    float* halfmax= (float*)w;  w += (size_t)BB * 2 * LL * 128 * 4; // 8MB
    __bf16* Wf[3];
    Wf[0] = (__bf16*)w; w += 65536 * 2;
    Wf[1] = (__bf16*)w; w += 65536 * 2;
    Wf[2] = (__bf16*)w; w += 65536 * 2;
    int*   e32    = (int*)w;    w += (size_t)2 * EE * 4;
    float* deg    = (float*)w;  w += LL * 4;
    int*   cnt    = (int*)w;    w += LL * 4;
    int*   rowptr = (int*)w;    w += (LL + 4) * 4;
    int*   cursor = (int*)w;    w += LL * 4;
    Edge*  edges  = (Edge*)w;   w += (size_t)EF * 8;
    float* dinv   = (float*)w;  w += LL * 4;
    float* gstats = (float*)w;  w += 8 * 512 * 4;   // [slot][sums 256 | sumsq 256]
    float* scb    = (float*)w;  w += 512 * 4;
    int*   flag   = (int*)w;    w += 256;

    // edge preprocessing
    detect_init_kernel<<<8, 256, 0, stream>>>((const int*)ei, flag, deg, cnt, gstats);
    conv_deg_kernel<<<(EE + 255) / 256, 256, 0, stream>>>(ei, flag, e32, deg, cnt);
    scan_dinv_kernel<<<1, 256, 0, stream>>>(cnt, deg, rowptr, cursor, dinv);
    fill_kernel<<<(EF + 255) / 256, 256, 0, stream>>>(e32, dinv, cursor, edges);

    // weight pre-pack + input transpose
    prep_w_all<<<36, 256, 0, stream>>>(W[0], W[1], W[2], Wf[0], Wf[1], Wf[2]);
    transpose_x<<<dim3(LL / 32, C0 / 32, GG), dim3(32, 8), 0, stream>>>(x, h0);

    // block 1
    gemm_mfma<64, false><<<dim3(LL / 64, GG), 256, 0, stream>>>(h0, amax, scb, Wf[0], hw);
    agg_half<<<4096, 256, 0, stream>>>(hw, bia[0], rowptr, edges, a, halfmax, gstats);
    combine_kernel<<<1024, 256, 0, stream>>>(halfmax, amax, gstats);
    bnfinal_kernel<<<1, 256, 0, stream>>>(gstats, gam[0], bet[0], scb);

    // block 2
    gemm_mfma<256, true><<<dim3(LL / 64, GG), 256, 0, stream>>>(a, amax, scb, Wf[1], hw);
    agg_half<<<4096, 256, 0, stream>>>(hw, bia[1], rowptr, edges, a, halfmax, gstats);
    combine_kernel<<<1024, 256, 0, stream>>>(halfmax, amax, gstats);
    bnfinal_kernel<<<1, 256, 0, stream>>>(gstats, gam[1], bet[1], scb);

    // block 3
    gemm_mfma<256, true><<<dim3(LL / 64, GG), 256, 0, stream>>>(a, amax, scb, Wf[2], hw);
    agg_half<<<4096, 256, 0, stream>>>(hw, bia[2], rowptr, edges, a, halfmax, gstats);
    combine_kernel<<<1024, 256, 0, stream>>>(halfmax, amax, gstats);
    bnfinal_kernel<<<1, 256, 0, stream>>>(gstats, gam[2], bet[2], scb);

    // fused BN + ReLU + transpose to output layout
    transpose_norm_out<<<dim3(LL / 64, CC / 64, GG), dim3(64, 8), 0, stream>>>(a, amax, scb, out);
}

// Round 7
// 555.383 us; speedup vs baseline: 1.0739x; 1.0739x over previous
//
#include <hip/hip_runtime.h>
#include <hip/hip_bf16.h>
#include <cstddef>
#include <cstdint>

#define BB 4
#define NN 16
#define GG 64          // BB*NN
#define LL 2048
#define EE 32768
#define EF (EE + LL)   // edges + self loops
#define C0 64
#define CC 256
#define EPS 1e-5f

typedef __bf16 bf16x8 __attribute__((ext_vector_type(8)));
typedef __bf16 bf16x4 __attribute__((ext_vector_type(4)));
typedef __bf16 bf16x2 __attribute__((ext_vector_type(2)));
typedef float f32x4 __attribute__((ext_vector_type(4)));

struct __align__(8) Edge { int col; float val; };

// ---------------- init: flag detect + deg/cnt init + gstats/ticket zero ----------------
// grid 16 x 256.

__global__ void detect_init_kernel(const int* __restrict__ ei, int* __restrict__ flag,
                                   float* __restrict__ deg, int* __restrict__ cnt,
                                   float* __restrict__ gstats, int* __restrict__ ticket) {
    int i = blockIdx.x * 256 + threadIdx.x;   // 0..4095
    if (i < LL) { deg[i] = 2.0f; cnt[i] = 1; }   // self-loop weight 2, one slot
    if (i < 4096) gstats[i] = 0.0f;               // 8 slots x 512
    if (i == 0) *ticket = 0;
    if (blockIdx.x == 0 && threadIdx.x < 64) {
        int t = threadIdx.x;
        int bad = 0;
        for (int k = t; k < 256; k += 64) bad |= (ei[2 * k + 1] != 0) ? 1 : 0;
        int any = __any(bad);
        if (t == 0) *flag = any ? 0 : 1;  // 1 => data is int64
    }
}

// convert edges to int32 AND accumulate degree
__global__ void conv_deg_kernel(const void* __restrict__ ei, const int* __restrict__ flag,
                                int* __restrict__ e32, float* __restrict__ deg,
                                int* __restrict__ cnt) {
    int e = blockIdx.x * 256 + threadIdx.x;
    if (e >= EE) return;
    int s, d;
    if (*flag) {
        s = (int)((const long long*)ei)[e];
        d = (int)((const long long*)ei)[EE + e];
    } else {
        s = ((const int*)ei)[e];
        d = ((const int*)ei)[EE + e];
    }
    e32[e] = s;
    e32[EE + e] = d;
    atomicAdd(&deg[d], 1.0f);
    atomicAdd(&cnt[d], 1);
}

// prefix-scan of cnt -> rowptr/cursor, plus dinv = rsqrt(deg)
__global__ void scan_dinv_kernel(const int* __restrict__ cnt, const float* __restrict__ deg,
                                 int* __restrict__ rowptr, int* __restrict__ cursor,
                                 float* __restrict__ dinv) {
    __shared__ int part[256];
    int t = threadIdx.x;
    int base = t * 8;
    int loc[8];
    int s = 0;
#pragma unroll
    for (int j = 0; j < 8; ++j) {
        loc[j] = s; s += cnt[base + j];
        dinv[base + j] = rsqrtf(deg[base + j]);
    }
    part[t] = s;
    __syncthreads();
    if (t == 0) {
        int run = 0;
        for (int i = 0; i < 256; ++i) { int v = part[i]; part[i] = run; run += v; }
    }
    __syncthreads();
    int off = part[t];
#pragma unroll
    for (int j = 0; j < 8; ++j) {
        int rp = off + loc[j];
        rowptr[base + j] = rp;
        cursor[base + j] = rp;
    }
    if (t == 255) rowptr[LL] = off + s;
}

__global__ void fill_kernel(const int* __restrict__ e32, const float* __restrict__ dinv,
                            int* __restrict__ cursor, Edge* __restrict__ edges) {
    int idx = blockIdx.x * 256 + threadIdx.x;
    if (idx >= EF) return;
    int s, d; float w;
    if (idx < EE) {
        s = e32[idx]; d = e32[EE + idx];
        w = dinv[s] * dinv[d];
    } else {
        int i = idx - EE;
        s = i; d = i;
        w = 2.0f * dinv[i] * dinv[i];
    }
    int pos = atomicAdd(&cursor[d], 1);
    edges[pos].col = s;
    edges[pos].val = w;
}

// ---------------- W pre-pack: all 3 weights in one launch ----------------

__global__ void prep_w_all(const float* __restrict__ W0, const float* __restrict__ W1,
                           const float* __restrict__ W2, __bf16* __restrict__ Wf0,
                           __bf16* __restrict__ Wf1, __bf16* __restrict__ Wf2) {
    int t = blockIdx.x * 256 + threadIdx.x;
    const float* W; __bf16* Wf;
    if (t < 1024)      { W = W0; Wf = Wf0; }
    else if (t < 5120) { W = W1; Wf = Wf1; t -= 1024; }
    else if (t < 9216) { W = W2; Wf = Wf2; t -= 5120; }
    else return;
    int lane = t & 63;
    int rest = t >> 6;
    int n16 = rest & 7;
    int ks = rest >> 3;
    int col = n16 * 16 + (lane & 15);
    int k0 = ks * 32 + (lane >> 4) * 8;
    bf16x8 v;
#pragma unroll
    for (int j = 0; j < 8; ++j) v[j] = (__bf16)W[(size_t)(k0 + j) * 128 + col];
    *(bf16x8*)(Wf + (size_t)t * 8) = v;
}

// ---------------- MFMA GEMM: hw[g][l][128] = act(A)[g][l][0:K] @ W[K][128] ----------------
// BN=false (block 1): A staged straight from x[g][64][2048] with in-LDS transpose.
// BN=true: A = relu(bn(concat(a_bf, amax_bf broadcast))) applied at staging (bf16 in).
// grid (LL/64, GG), 256 threads (4 waves).

template <int K, bool BN>
__global__ __launch_bounds__(256) void gemm_mfma(const void* __restrict__ A0v,
                                                 const __bf16* __restrict__ amax,
                                                 const float* __restrict__ scb,
                                                 const __bf16* __restrict__ Wf,
                                                 __bf16* __restrict__ hw) {
    const int g = blockIdx.y;
    const int l0 = blockIdx.x * 64;
    const int tid = threadIdx.x;
    const int wid = tid >> 6;
    const int lane = tid & 63;
    __shared__ __align__(16) float smem[64 * 132];   // 33.8KB; front 8KB doubles as As
    __bf16* As = (__bf16*)smem;

    f32x4 acc[8];
#pragma unroll
    for (int nf = 0; nf < 8; ++nf) acc[nf] = (f32x4){0.f, 0.f, 0.f, 0.f};

    for (int kt = 0; kt < K / 64; ++kt) {
        // ---- stage A tile [64 rows][64 k] -> bf16 LDS, XOR-swizzled ----
        if constexpr (!BN) {
            // transpose from x: rows=l, k=c. thread: l=tid&63, cq=tid>>6
            const float* x = (const float*)A0v;
            const int l = tid & 63, cq = tid >> 6;
#pragma unroll
            for (int it = 0; it < 4; ++it) {
                int cbase = it * 16 + cq * 4;
                bf16x4 pv;
#pragma unroll
                for (int j = 0; j < 4; ++j)
                    pv[j] = (__bf16)x[((size_t)g * C0 + cbase + j) * LL + l0 + l];
                *(bf16x4*)(&As[l * 64 + (cbase ^ ((l & 7) << 3))]) = pv;
            }
        } else {
            const __bf16* a = (const __bf16*)A0v;
#pragma unroll
            for (int it = 0; it < 2; ++it) {
                int f8 = tid + it * 256;       // 0..511
                int row = f8 >> 3;             // 0..63
                int oct = f8 & 7;              // 0..7
                int gk = kt * 64 + oct * 8;
                bf16x8 v;
                if (gk < 128)
                    v = *(const bf16x8*)(a + ((size_t)g * LL + l0 + row) * 128 + gk);
                else
                    v = *(const bf16x8*)(amax + ((size_t)(g >> 4) * LL + l0 + row) * 128 + (gk - 128));
                float4 s0 = *(const float4*)(scb + gk);
                float4 s1 = *(const float4*)(scb + gk + 4);
                float4 b0 = *(const float4*)(scb + 256 + gk);
                float4 b1 = *(const float4*)(scb + 256 + gk + 4);
                bf16x8 pv;
                pv[0] = (__bf16)fmaxf(fmaf((float)v[0], s0.x, b0.x), 0.f);
                pv[1] = (__bf16)fmaxf(fmaf((float)v[1], s0.y, b0.y), 0.f);
                pv[2] = (__bf16)fmaxf(fmaf((float)v[2], s0.z, b0.z), 0.f);
                pv[3] = (__bf16)fmaxf(fmaf((float)v[3], s0.w, b0.w), 0.f);
                pv[4] = (__bf16)fmaxf(fmaf((float)v[4], s1.x, b1.x), 0.f);
                pv[5] = (__bf16)fmaxf(fmaf((float)v[5], s1.y, b1.y), 0.f);
                pv[6] = (__bf16)fmaxf(fmaf((float)v[6], s1.z, b1.z), 0.f);
                pv[7] = (__bf16)fmaxf(fmaf((float)v[7], s1.w, b1.w), 0.f);
                *(bf16x8*)(&As[row * 64 + ((oct * 8) ^ ((row & 7) << 3))]) = pv;
            }
        }
        __syncthreads();
        // ---- MFMA over the 2 k-steps of this tile ----
#pragma unroll
        for (int ks2 = 0; ks2 < 2; ++ks2) {
            const int row = wid * 16 + (lane & 15);
            const int kk = ks2 * 32 + (lane >> 4) * 8;
            bf16x8 af = *(const bf16x8*)(&As[row * 64 + (kk ^ ((row & 7) << 3))]);
            const int ksg = kt * 2 + ks2;
            const __bf16* wp = Wf + (size_t)ksg * 8 * 512 + lane * 8;
#pragma unroll
            for (int nf = 0; nf < 8; ++nf) {
                bf16x8 bfr = *(const bf16x8*)(wp + nf * 512);
                acc[nf] = __builtin_amdgcn_mfma_f32_16x16x32_bf16(af, bfr, acc[nf], 0, 0, 0);
            }
        }
        __syncthreads();
    }
    // ---- epilogue: acc -> LDS (f32, padded) -> coalesced bf16x8 stores ----
#pragma unroll
    for (int nf = 0; nf < 8; ++nf) {
        int col = nf * 16 + (lane & 15);
#pragma unroll
        for (int j = 0; j < 4; ++j) {
            int row = wid * 16 + (lane >> 4) * 4 + j;
            smem[row * 132 + col] = acc[nf][j];
        }
    }
    __syncthreads();
    const int row = tid >> 2, seg = tid & 3;
    __bf16* dst = hw + ((size_t)g * LL + l0 + row) * 128 + seg * 32;
    const float* src = smem + row * 132 + seg * 32;
#pragma unroll
    for (int q = 0; q < 4; ++q) {
        bf16x8 o;
#pragma unroll
        for (int i = 0; i < 8; ++i) o[i] = (__bf16)src[q * 8 + i];
        *(bf16x8*)(dst + q * 8) = o;
    }
}

// ---------------- aggregation: a_bf[g][l][f] = bias[f] + sum_e val*hw[g][col][f] ----------------
// One wave per node. grp=lane>>4 handles 4 edges per 16-edge iter (4x 16B gathers in
// flight); lane&15 owns a channel octet. Butterfly over grps at the end. XCD-pinned so
// each graph's 512KB hw slice stays in one XCD's L2. grid GG*LL/4, block 256.

__global__ __launch_bounds__(256) void agg_kernel(const __bf16* __restrict__ hw,
                                                  const float* __restrict__ bias,
                                                  const int* __restrict__ rowptr,
                                                  const Edge* __restrict__ edges,
                                                  __bf16* __restrict__ aout) {
    const int lane = threadIdx.x & 63;
    const int grp = lane >> 4;      // edge sub-group 0..3
    const int ch16 = lane & 15;     // channel octet
    const int bid = blockIdx.x;
    const int xcd = bid & 7;
    const int slot = bid >> 3;                 // 0..4095
    const int gswz = ((slot >> 9) << 3) + xcd; // graph pinned to xcd
    const int within = slot & 511;
    int node = (gswz << 11) + within * 4 + (threadIdx.x >> 6);  // g*LL + l
    node = __builtin_amdgcn_readfirstlane(node);
    const int g = node >> 11, l = node & (LL - 1);
    const __bf16* __restrict__ base = hw + (size_t)g * LL * 128 + ch16 * 8;
    const int j0 = rowptr[l];
    const int deg = rowptr[l + 1] - j0;

    float acc[8];
#pragma unroll
    for (int j = 0; j < 8; ++j) acc[j] = 0.0f;

    for (int d0 = 0; d0 < deg; d0 += 64) {
        const int cntE = min(64, deg - d0);
        Edge e;
        e.col = 0; e.val = 0.0f;   // masked lanes contribute 0 via val=0
        if (lane < cntE) e = edges[j0 + d0 + lane];
        int d = 0;
        for (; d + 16 <= cntE; d += 16) {
            int i1 = d + grp, i2 = d + 4 + grp, i3 = d + 8 + grp, i4 = d + 12 + grp;
            int c1 = __shfl(e.col, i1); float w1 = __shfl(e.val, i1);
            int c2 = __shfl(e.col, i2); float w2 = __shfl(e.val, i2);
            int c3 = __shfl(e.col, i3); float w3 = __shfl(e.val, i3);
            int c4 = __shfl(e.col, i4); float w4 = __shfl(e.val, i4);
            bf16x8 v1 = *(const bf16x8*)(base + (size_t)c1 * 128);
            bf16x8 v2 = *(const bf16x8*)(base + (size_t)c2 * 128);
            bf16x8 v3 = *(const bf16x8*)(base + (size_t)c3 * 128);
            bf16x8 v4 = *(const bf16x8*)(base + (size_t)c4 * 128);
#pragma unroll
            for (int j = 0; j < 8; ++j) acc[j] = fmaf(w1, (float)v1[j], acc[j]);
#pragma unroll
            for (int j = 0; j < 8; ++j) acc[j] = fmaf(w2, (float)v2[j], acc[j]);
#pragma unroll
            for (int j = 0; j < 8; ++j) acc[j] = fmaf(w3, (float)v3[j], acc[j]);
#pragma unroll
            for (int j = 0; j < 8; ++j) acc[j] = fmaf(w4, (float)v4[j], acc[j]);
        }
        for (; d < cntE; d += 4) {
            int i1 = d + grp;
            int c1 = __shfl(e.col, i1); float w1 = __shfl(e.val, i1);
            bf16x8 v1 = *(const bf16x8*)(base + (size_t)c1 * 128);
#pragma unroll
            for (int j = 0; j < 8; ++j) acc[j] = fmaf(w1, (float)v1[j], acc[j]);
        }
    }
    // butterfly over the 4 edge groups
#pragma unroll
    for (int j = 0; j < 8; ++j) {
        acc[j] += __shfl_xor(acc[j], 16);
        acc[j] += __shfl_xor(acc[j], 32);
    }
    if (grp == 0) {
        float4 b0 = *(const float4*)(bias + ch16 * 8);
        float4 b1 = *(const float4*)(bias + ch16 * 8 + 4);
        bf16x8 o;
        o[0] = (__bf16)(acc[0] + b0.x); o[1] = (__bf16)(acc[1] + b0.y);
        o[2] = (__bf16)(acc[2] + b0.z); o[3] = (__bf16)(acc[3] + b0.w);
        o[4] = (__bf16)(acc[4] + b1.x); o[5] = (__bf16)(acc[5] + b1.y);
        o[6] = (__bf16)(acc[6] + b1.z); o[7] = (__bf16)(acc[7] + b1.w);
        *(bf16x8*)(aout + (size_t)node * 128 + ch16 * 8) = o;
    }
}

// ---------------- max over n + BN stats + (last block) BN finalize ----------------
// a: [g][l][128] bf16. grid 512 blocks x 256 thr. thread: c2=t&63 (ch pair), lq=t>>6.
// Ticket-fused finalize: last block computes scb from gstats (atomicExch read+clear).

__global__ __launch_bounds__(256) void maxstats_kernel(const __bf16* __restrict__ a,
                                                       __bf16* __restrict__ amax,
                                                       float* __restrict__ gstats,
                                                       int* __restrict__ ticket,
                                                       const float* __restrict__ gamma,
                                                       const float* __restrict__ beta,
                                                       float* __restrict__ scb) {
    __shared__ float bl[512];
    __shared__ int lastflag;
    const int t = threadIdx.x;
    bl[t] = 0.f; bl[256 + t] = 0.f;
    __syncthreads();
    const int bb = blockIdx.x >> 7;     // 128 blocks per b
    const int lt = blockIdx.x & 127;
    const int c2 = t & 63;              // ch = c2*2
    const int lq = t >> 6;              // 0..3
    const int l0 = lt * 16 + lq * 4;
    float sx = 0.f, sy = 0.f, qx = 0.f, qy = 0.f;
    float sax = 0.f, say = 0.f, qax = 0.f, qay = 0.f;
#pragma unroll
    for (int i = 0; i < 4; ++i) {
        int l = l0 + i;
        float mx = -3.402823466e38f, my = -3.402823466e38f;
#pragma unroll
        for (int n = 0; n < NN; ++n) {
            bf16x2 v = *(const bf16x2*)(a + ((size_t)(bb * NN + n) * LL + l) * 128 + c2 * 2);
            float v0 = (float)v[0], v1 = (float)v[1];
            mx = fmaxf(mx, v0); my = fmaxf(my, v1);
            sx += v0; sy += v1;
            qx = fmaf(v0, v0, qx); qy = fmaf(v1, v1, qy);
        }
        bf16x2 mv = {(__bf16)mx, (__bf16)my};
        *(bf16x2*)(amax + ((size_t)bb * LL + l) * 128 + c2 * 2) = mv;
        sax += mx; say += my;
        qax = fmaf(mx, mx, qax); qay = fmaf(my, my, qay);
    }
    atomicAdd(&bl[c2 * 2], sx);        atomicAdd(&bl[c2 * 2 + 1], sy);
    atomicAdd(&bl[128 + c2 * 2], sax); atomicAdd(&bl[128 + c2 * 2 + 1], say);
    atomicAdd(&bl[256 + c2 * 2], qx);  atomicAdd(&bl[256 + c2 * 2 + 1], qy);
    atomicAdd(&bl[384 + c2 * 2], qax); atomicAdd(&bl[384 + c2 * 2 + 1], qay);
    __syncthreads();
    const int slot = blockIdx.x & 7;
    atomicAdd(&gstats[slot * 512 + t], bl[t]);
    atomicAdd(&gstats[slot * 512 + 256 + t], bl[256 + t]);
    __threadfence();
    if (t == 0) lastflag = (atomicAdd(ticket, 1) == 511) ? 1 : 0;
    __syncthreads();
    if (lastflag) {
        float sm = 0.f, sq = 0.f;
#pragma unroll
        for (int sl = 0; sl < 8; ++sl) {
            sm += atomicExch(&gstats[sl * 512 + t], 0.f);
            sq += atomicExch(&gstats[sl * 512 + 256 + t], 0.f);
        }
        float cntv = (t < 128) ? (float)(BB * NN * LL) : (float)(BB * LL);
        float mean = sm / cntv;
        float var = sq / cntv - mean * mean;
        float sc = gamma[t] * rsqrtf(var + EPS);
        scb[t] = sc;
        scb[256 + t] = beta[t] - mean * sc;
        if (t == 0) *ticket = 0;
    }
}

// ---------------- final: out[g][f][l] = relu(bn(concat(a, amax))) transposed ----------------
// grid (LL/64, CC/64, GG), block (64,8).

__global__ void transpose_norm_out(const __bf16* __restrict__ a, const __bf16* __restrict__ amax,
                                   const float* __restrict__ scb, float* __restrict__ out) {
    __shared__ float t[64][65];
    int g = blockIdx.z, f0 = blockIdx.y * 64, l0 = blockIdx.x * 64;
    int tx = threadIdx.x, ty = threadIdx.y;  // 64 x 8
    int f = f0 + tx;
    float s = scb[f], b = scb[256 + f];
#pragma unroll
    for (int i = ty; i < 64; i += 8) {
        int l = l0 + i;
        float v;
        if (f0 < 128)
            v = (float)a[((size_t)g * LL + l) * 128 + f];
        else
            v = (float)amax[((size_t)(g >> 4) * LL + l) * 128 + (f - 128)];
        t[i][tx] = fmaxf(fmaf(v, s, b), 0.f);
    }
    __syncthreads();
    float* op = out + ((size_t)g * CC + f0) * LL + l0;
#pragma unroll
    for (int i = ty; i < 64; i += 8) op[(size_t)i * LL + tx] = t[tx][i];
}

// ---------------- launch ----------------

extern "C" void kernel_launch(void* const* d_in, const int* in_sizes, int n_in,
                              void* d_out, int out_size, void* d_ws, size_t ws_size,
                              hipStream_t stream) {
    const float* x = (const float*)d_in[0];
    const void* ei = d_in[1];
    const float* W[3] = {(const float*)d_in[2], (const float*)d_in[4], (const float*)d_in[6]};
    const float* bia[3] = {(const float*)d_in[3], (const float*)d_in[5], (const float*)d_in[7]};
    const float* gam[3] = {(const float*)d_in[8], (const float*)d_in[10], (const float*)d_in[12]};
    const float* bet[3] = {(const float*)d_in[9], (const float*)d_in[11], (const float*)d_in[13]};
    float* out = (float*)d_out;

    char* w = (char*)d_ws;
    __bf16* a_bf  = (__bf16*)w; w += (size_t)GG * LL * 128 * 2;   // 33.5MB
    __bf16* hw    = (__bf16*)w; w += (size_t)GG * LL * 128 * 2;   // 33.5MB
    __bf16* amax  = (__bf16*)w; w += (size_t)BB * LL * 128 * 2;   // 2MB
    __bf16* Wf[3];
    Wf[0] = (__bf16*)w; w += 65536 * 2;
    Wf[1] = (__bf16*)w; w += 65536 * 2;
    Wf[2] = (__bf16*)w; w += 65536 * 2;
    int*   e32    = (int*)w;    w += (size_t)2 * EE * 4;
    float* deg    = (float*)w;  w += LL * 4;
    int*   cnt    = (int*)w;    w += LL * 4;
    int*   rowptr = (int*)w;    w += (LL + 4) * 4;
    int*   cursor = (int*)w;    w += LL * 4;
    Edge*  edges  = (Edge*)w;   w += (size_t)EF * 8;
    float* dinv   = (float*)w;  w += LL * 4;
    float* gstats = (float*)w;  w += 8 * 512 * 4;   // [slot][sums 256 | ssq 256]
    float* scb    = (float*)w;  w += 512 * 4;
    int*   flag   = (int*)w;    w += 256;
    int*   ticket = (int*)w;    w += 256;

    // edge preprocessing
    detect_init_kernel<<<16, 256, 0, stream>>>((const int*)ei, flag, deg, cnt, gstats, ticket);
    conv_deg_kernel<<<(EE + 255) / 256, 256, 0, stream>>>(ei, flag, e32, deg, cnt);
    scan_dinv_kernel<<<1, 256, 0, stream>>>(cnt, deg, rowptr, cursor, dinv);
    fill_kernel<<<(EF + 255) / 256, 256, 0, stream>>>(e32, dinv, cursor, edges);
    prep_w_all<<<36, 256, 0, stream>>>(W[0], W[1], W[2], Wf[0], Wf[1], Wf[2]);

    // block 1 (GEMM stages straight from x, transposing in LDS)
    gemm_mfma<64, false><<<dim3(LL / 64, GG), 256, 0, stream>>>(x, amax, scb, Wf[0], hw);
    agg_kernel<<<GG * LL / 4, 256, 0, stream>>>(hw, bia[0], rowptr, edges, a_bf);
    maxstats_kernel<<<512, 256, 0, stream>>>(a_bf, amax, gstats, ticket, gam[0], bet[0], scb);

    // block 2
    gemm_mfma<256, true><<<dim3(LL / 64, GG), 256, 0, stream>>>(a_bf, amax, scb, Wf[1], hw);
    agg_kernel<<<GG * LL / 4, 256, 0, stream>>>(hw, bia[1], rowptr, edges, a_bf);
    maxstats_kernel<<<512, 256, 0, stream>>>(a_bf, amax, gstats, ticket, gam[1], bet[1], scb);

    // block 3
    gemm_mfma<256, true><<<dim3(LL / 64, GG), 256, 0, stream>>>(a_bf, amax, scb, Wf[2], hw);
    agg_kernel<<<GG * LL / 4, 256, 0, stream>>>(hw, bia[2], rowptr, edges, a_bf);
    maxstats_kernel<<<512, 256, 0, stream>>>(a_bf, amax, gstats, ticket, gam[2], bet[2], scb);

    // fused BN + ReLU + transpose to output layout
    transpose_norm_out<<<dim3(LL / 64, CC / 64, GG), dim3(64, 8), 0, stream>>>(a_bf, amax, scb, out);
}